// Round 5
// baseline (7381.927 us; speedup 1.0000x reference)
//
#include <hip/hip_runtime.h>
#include <hip/hip_fp16.h>

typedef _Float16 f16;
typedef _Float16 f16x8 __attribute__((ext_vector_type(8)));
typedef __fp16 h16x2 __attribute__((ext_vector_type(2)));
typedef float f32x4 __attribute__((ext_vector_type(4)));
typedef float f32x16 __attribute__((ext_vector_type(16)));

#define LOG2E 1.4426950408889634f
#define NSL 0.2f

// ---------------- Kernel 1: graph -> j-major transposed bitmask (+ init M2e) ----------------
// maskJ[jw][i] bit b = (graph[jw*32+b][i] > 0)   (j-major: k_main reads 32 consecutive i -> 128 B)
__global__ __launch_bounds__(256) void k_mask(const int* __restrict__ graph,
                                              unsigned int* __restrict__ maskJ,
                                              unsigned int* __restrict__ M2e) {
    if (blockIdx.x == 0 && threadIdx.x < 8) M2e[threadIdx.x] = 0x007FFFFFu;  // enc(-inf)
    __shared__ unsigned long long bal[4][64];
    int w = threadIdx.x >> 6;
    int lane = threadIdx.x & 63;
    int gw = blockIdx.x * 4 + w;
    int ti = gw & 63, tj = gw >> 6;
    int i0 = ti * 64, j0 = tj * 64;
    #pragma unroll 8
    for (int k = 0; k < 64; k++) {
        int g = graph[(j0 + k) * 4096 + i0 + lane];
        unsigned long long b = __ballot(g > 0);
        if (lane == 0) bal[w][k] = b;
    }
    __syncthreads();
    unsigned long long word = 0;
    #pragma unroll 8
    for (int k = 0; k < 64; k++) {
        word |= ((bal[w][k] >> lane) & 1ull) << k;
    }
    int jw = j0 >> 5;
    maskJ[(size_t)jw * 4096 + i0 + lane]       = (unsigned int)word;
    maskJ[(size_t)(jw + 1) * 4096 + i0 + lane] = (unsigned int)(word >> 32);
}

// ---------------- Kernel 2 (fused prep): xcvt + swizzled weight transposes ----------------
// out[((m>>4)*S + f)*16 + (m&15)] = in[m][f]   (direct MFMA-fragment layout)
__device__ void dev_transpose_sw(const float* __restrict__ in, f16* __restrict__ out,
                                 int C, int S, int bxx, int byy, int tid) {
    __shared__ float tile[32][33];
    int tx = tid & 31, ty = tid >> 5;
    int c0 = bxx * 32, r0 = byy * 32;
    for (int rr = ty; rr < 32; rr += 8)
        tile[rr][tx] = in[(r0 + rr) * C + c0 + tx];
    __syncthreads();
    for (int rr = ty; rr < 32; rr += 8) {
        int m = r0 + tx, f = c0 + rr;
        out[(size_t)((m >> 4) * S + f) * 16 + (m & 15)] = (f16)tile[tx][rr];
    }
}

__global__ __launch_bounds__(256) void k_pre(const float* __restrict__ x,
                                             f16* __restrict__ xh2,
                                             const float* __restrict__ W,
                                             f16* __restrict__ Wht2,
                                             const float* __restrict__ Wr,
                                             f16* __restrict__ Wrt2) {
    int bx = blockIdx.x;
    int tid = threadIdx.x;
    if (bx < 512) {
        int id = bx * 256 + tid;   // 131072
        int row = id & 4095, kt = id >> 12;
        const float4* xs = (const float4*)(x + (size_t)row * 512 + kt * 16);
        float4 u0 = xs[0], u1 = xs[1], u2 = xs[2], u3 = xs[3];
        union { int4 a[2]; h16x2 p[8]; } px;
        px.p[0] = __builtin_amdgcn_cvt_pkrtz(u0.x, u0.y);
        px.p[1] = __builtin_amdgcn_cvt_pkrtz(u0.z, u0.w);
        px.p[2] = __builtin_amdgcn_cvt_pkrtz(u1.x, u1.y);
        px.p[3] = __builtin_amdgcn_cvt_pkrtz(u1.z, u1.w);
        px.p[4] = __builtin_amdgcn_cvt_pkrtz(u2.x, u2.y);
        px.p[5] = __builtin_amdgcn_cvt_pkrtz(u2.z, u2.w);
        px.p[6] = __builtin_amdgcn_cvt_pkrtz(u3.x, u3.y);
        px.p[7] = __builtin_amdgcn_cvt_pkrtz(u3.z, u3.w);
        int4* d = (int4*)(xh2 + ((size_t)kt * 4096 + row) * 16);
        d[0] = px.a[0]; d[1] = px.a[1];
    } else if (bx < 1024) {
        int id = bx - 512;                       // W: [4096 m][128 f] -> Wht2 [(m>>4)*128+f][m&15]
        dev_transpose_sw(W, Wht2, 128, 128, id & 3, id >> 2, tid);
    } else {
        int id = bx - 1024;                      // Wr: [512 k][1024 f] -> Wrt2 [(k>>4)*1024+f][k&15]
        dev_transpose_sw(Wr, Wrt2, 1024, 1024, id & 31, id >> 5, tid);
    }
}

// ---------------- Kernel 3: hbT2 swizzled [h][(j>>4)*128+f][j&15] ----------------
__global__ __launch_bounds__(256) void k_gemm_h(const f16* __restrict__ xh2,
                                                const f16* __restrict__ Wht2,
                                                f16* __restrict__ hbT2) {
    int bx = blockIdx.x;
    int h = bx & 7, jb = bx >> 3;
    int j0 = jb * 64;
    int tid = threadIdx.x;
    int w = tid >> 6, lane = tid & 63;
    int ln = lane & 15, q = lane >> 4;
    f32x4 acc[2][4] = {};
    for (int k0 = 0; k0 < 512; k0 += 32) {
        int kt = (k0 >> 4) + (q >> 1);
        int ko = (q & 1) * 8;
        f16x8 a0 = *(const f16x8*)(Wht2 + ((size_t)(h * 512 + k0) * 8 /* (k0>>4)*128 */
                                           + (size_t)(q >> 1) * 128 + w * 32 + ln) * 16 + ko);
        f16x8 a1 = *(const f16x8*)(Wht2 + ((size_t)(h * 512 + k0) * 8
                                           + (size_t)(q >> 1) * 128 + w * 32 + 16 + ln) * 16 + ko);
        f16x8 bfr[4];
        #pragma unroll
        for (int nt = 0; nt < 4; nt++) {
            bfr[nt] = *(const f16x8*)(xh2 + ((size_t)kt * 4096 + j0 + nt * 16 + ln) * 16 + ko);
        }
        #pragma unroll
        for (int nt = 0; nt < 4; nt++) {
            acc[0][nt] = __builtin_amdgcn_mfma_f32_16x16x32_f16(a0, bfr[nt], acc[0][nt], 0, 0, 0);
            acc[1][nt] = __builtin_amdgcn_mfma_f32_16x16x32_f16(a1, bfr[nt], acc[1][nt], 0, 0, 0);
        }
    }
    #pragma unroll
    for (int mt = 0; mt < 2; mt++)
        #pragma unroll
        for (int nt = 0; nt < 4; nt++) {
            #pragma unroll
            for (int r = 0; r < 4; r++) {
                int f = w * 32 + mt * 16 + q * 4 + r;
                hbT2[(size_t)h * 524288 + (size_t)((j0 >> 4) + nt) * 2048 + f * 16 + ln] =
                    (f16)acc[mt][nt][r];
            }
        }
}

// ---------------- Kernel 4: a2/b2 + per-head atomic max of b2 (encoded) ----------------
__global__ __launch_bounds__(256) void k_ab(const f16* __restrict__ hbT2,
                                            const float* __restrict__ wi,
                                            const float* __restrict__ wj,
                                            float* __restrict__ a2, float* __restrict__ b2,
                                            unsigned int* __restrict__ M2e) {
    __shared__ float swi[128], swj[128], red[256];
    int b = blockIdx.x;
    int h = b & 7, jc = b >> 3;
    int tid = threadIdx.x;
    if (tid < 128) { swi[tid] = wi[h * 128 + tid]; swj[tid] = wj[h * 128 + tid]; }
    __syncthreads();
    int j = jc * 256 + tid;
    float pa = 0.f, pb = 0.f;
    #pragma unroll 8
    for (int f = 0; f < 128; f++) {
        float v = (float)hbT2[(size_t)h * 524288 + (size_t)((j >> 4) * 128 + f) * 16 + (j & 15)];
        pa += v * swi[f];
        pb += v * swj[f];
    }
    a2[h * 4096 + j] = pa * LOG2E;
    float bb = pb * LOG2E;
    b2[h * 4096 + j] = bb;
    red[tid] = bb;
    __syncthreads();
    for (int s = 128; s > 0; s >>= 1) {
        if (tid < s) red[tid] = fmaxf(red[tid], red[tid + s]);
        __syncthreads();
    }
    if (tid == 0) {
        unsigned u = __float_as_uint(red[0]);
        unsigned enc = (u & 0x80000000u) ? ~u : (u | 0x80000000u);
        atomicMax(&M2e[h], enc);
    }
}

// ---------------- Kernel 5: exp tables ----------------
__global__ __launch_bounds__(256) void k_prep(const float* __restrict__ a2,
                                              const float* __restrict__ b2,
                                              const unsigned int* __restrict__ M2e,
                                              float* __restrict__ ABpre,
                                              float* __restrict__ Bpre) {
    int id = blockIdx.x * 256 + threadIdx.x;   // 32768
    int h = id >> 12;
    unsigned enc = M2e[h];
    unsigned u = (enc & 0x80000000u) ? (enc & 0x7FFFFFFFu) : ~enc;
    float M2 = __uint_as_float(u);
    float av = a2[id];
    float t = av + M2;
    float m2 = fmaxf(t, NSL * t);
    ((float2*)ABpre)[id] = make_float2(exp2f(av - m2), exp2f(NSL * av - m2));
    float bv = b2[id];
    ((float2*)Bpre)[id] = make_float2(exp2f(bv), exp2f(NSL * bv));
}

// ---------------- Kernel 6: main — zero-LDS-staging, register-prefetched B-frags ----------------
// Block = (h=bx&7 XCD-pinned, 32-i strip). Wave w = j-quarter (1024 j). 32x32x16 MFMA.
// B-frags load DIRECTLY from L2-resident swizzled hbT2 (contiguous 1 KB/instr), dbuf in regs.
// No barriers in j-loop. Denominator via per-lane VALU adds. Cross-wave reduce in epilogue only.
__global__ __launch_bounds__(256, 3) void k_main(const f16* __restrict__ xh2,
                                                 const f16* __restrict__ hbT2,
                                                 const f16* __restrict__ Wrt2,
                                                 const unsigned int* __restrict__ maskJ,
                                                 const float* __restrict__ ABpre,
                                                 const float* __restrict__ Bpre,
                                                 const float* __restrict__ bias,
                                                 float* __restrict__ out) {
    __shared__ float xred[2][64 * 68];   // 34816 B, 16B-aligned rows (68*4=272=16*17)
    __shared__ float dred[128];

    int bx = blockIdx.x;
    int h = bx & 7, it = bx >> 3;   // 128 i-strips
    int i0 = it * 32;
    int tid = threadIdx.x;
    int w = tid >> 6, lane = tid & 63;
    int l31 = lane & 31, half = lane >> 5;
    int i = i0 + l31;

    float2 Av = *(const float2*)(ABpre + 2 * (h * 4096 + i));
    float Ai = Av.x, Ai2 = Av.y;

    f32x16 acc0 = {}, acc1 = {}, acc2 = {}, acc3 = {};
    float dsum = 0.f;

    int J0 = w * 1024;
    const f16* bb = hbT2 + (size_t)h * 524288 + ((size_t)(J0 >> 4) * 128 + l31) * 16 + half * 8;
    const float* bp0 = Bpre + 2 * (h * 4096 + J0) + half * 16;
    const unsigned int* mrow = maskJ + (size_t)(J0 >> 5) * 4096 + i;

    f16x8 bfr[2][4];
    #pragma unroll
    for (int ft = 0; ft < 4; ft++) bfr[0][ft] = *(const f16x8*)(bb + ft * 512);

    for (int t = 0; t < 64; t++) {
        int cur = t & 1;
        if (t < 63) {   // register prefetch, distance 1
            const f16* s = bb + (size_t)(t + 1) * 2048;
            #pragma unroll
            for (int ft = 0; ft < 4; ft++) bfr[cur ^ 1][ft] = *(const f16x8*)(s + ft * 512);
        }
        unsigned mw = mrow[(size_t)(t >> 1) * 4096] >> (((t & 1) << 4) + (half << 3));
        const float4* bp = (const float4*)(bp0 + t * 32);
        float4 q0 = bp[0], q1 = bp[1], q2 = bp[2], q3 = bp[3];

        union { f16x8 v; h16x2 p[4]; } af;
        float e0, e1;
        e0 = fmaxf(Ai * q0.x, Ai2 * q0.y); e1 = fmaxf(Ai * q0.z, Ai2 * q0.w);
        e0 = (mw & 1u) ? e0 : 0.f;  e1 = (mw & 2u) ? e1 : 0.f;
        dsum += e0 + e1; af.p[0] = __builtin_amdgcn_cvt_pkrtz(e0, e1);
        e0 = fmaxf(Ai * q1.x, Ai2 * q1.y); e1 = fmaxf(Ai * q1.z, Ai2 * q1.w);
        e0 = (mw & 4u) ? e0 : 0.f;  e1 = (mw & 8u) ? e1 : 0.f;
        dsum += e0 + e1; af.p[1] = __builtin_amdgcn_cvt_pkrtz(e0, e1);
        e0 = fmaxf(Ai * q2.x, Ai2 * q2.y); e1 = fmaxf(Ai * q2.z, Ai2 * q2.w);
        e0 = (mw & 16u) ? e0 : 0.f; e1 = (mw & 32u) ? e1 : 0.f;
        dsum += e0 + e1; af.p[2] = __builtin_amdgcn_cvt_pkrtz(e0, e1);
        e0 = fmaxf(Ai * q3.x, Ai2 * q3.y); e1 = fmaxf(Ai * q3.z, Ai2 * q3.w);
        e0 = (mw & 64u) ? e0 : 0.f; e1 = (mw & 128u) ? e1 : 0.f;
        dsum += e0 + e1; af.p[3] = __builtin_amdgcn_cvt_pkrtz(e0, e1);

        acc0 = __builtin_amdgcn_mfma_f32_32x32x16_f16(af.v, bfr[cur][0], acc0, 0, 0, 0);
        acc1 = __builtin_amdgcn_mfma_f32_32x32x16_f16(af.v, bfr[cur][1], acc1, 0, 0, 0);
        acc2 = __builtin_amdgcn_mfma_f32_32x32x16_f16(af.v, bfr[cur][2], acc2, 0, 0, 0);
        acc3 = __builtin_amdgcn_mfma_f32_32x32x16_f16(af.v, bfr[cur][3], acc3, 0, 0, 0);
    }

    // ---- denominator: combine j-halves in-wave, then cross-wave via LDS ----
    dsum += __shfl(dsum, lane ^ 32);
    if (lane < 32) dred[w * 32 + l31] = dsum;
    __syncthreads();
    {
        float inv[16];
        #pragma unroll
        for (int r = 0; r < 16; r++) {
            int row = (r & 3) + 8 * (r >> 2) + 4 * half;
            float s = dred[row] + dred[32 + row] + dred[64 + row] + dred[96 + row];
            inv[r] = 1.0f / s;
        }
        #pragma unroll
        for (int r = 0; r < 16; r++) {
            acc0[r] *= inv[r]; acc1[r] *= inv[r]; acc2[r] *= inv[r]; acc3[r] *= inv[r];
        }
    }

    // ---- residual: acc += x @ Wr[:, h-slice]; k-quarter per wave, direct fragment loads ----
    {
        int k0b = w * 128;
        #pragma unroll
        for (int kt = 0; kt < 8; kt++) {
            int k0 = k0b + kt * 16;
            f16x8 ax = *(const f16x8*)(xh2 + ((size_t)(k0 >> 4) * 4096 + i) * 16 + half * 8);
            const f16* wb = Wrt2 + ((size_t)(k0 >> 4) * 1024 + h * 128 + l31) * 16 + half * 8;
            acc0 = __builtin_amdgcn_mfma_f32_32x32x16_f16(ax, *(const f16x8*)(wb), acc0, 0, 0, 0);
            acc1 = __builtin_amdgcn_mfma_f32_32x32x16_f16(ax, *(const f16x8*)(wb + 512), acc1, 0, 0, 0);
            acc2 = __builtin_amdgcn_mfma_f32_32x32x16_f16(ax, *(const f16x8*)(wb + 1024), acc2, 0, 0, 0);
            acc3 = __builtin_amdgcn_mfma_f32_32x32x16_f16(ax, *(const f16x8*)(wb + 1536), acc3, 0, 0, 0);
        }
    }

    // ---- cross-wave O reduction: (w2,w3)->(w0,w1), then w1->w0; w0 stores ----
    union uu { f32x16 v; f32x4 q[4]; };
    uu u0, u1, u2, u3;
    u0.v = acc0; u1.v = acc1; u2.v = acc2; u3.v = acc3;
    __syncthreads();
    if (w >= 2) {
        float* dp = xred[w - 2] + lane * 68;
        #pragma unroll
        for (int k4 = 0; k4 < 4; k4++) {
            *(f32x4*)(dp + k4 * 4)      = u0.q[k4];
            *(f32x4*)(dp + 16 + k4 * 4) = u1.q[k4];
            *(f32x4*)(dp + 32 + k4 * 4) = u2.q[k4];
            *(f32x4*)(dp + 48 + k4 * 4) = u3.q[k4];
        }
    }
    __syncthreads();
    if (w < 2) {
        const float* dp = xred[w] + lane * 68;
        #pragma unroll
        for (int k4 = 0; k4 < 4; k4++) {
            u0.q[k4] += *(const f32x4*)(dp + k4 * 4);
            u1.q[k4] += *(const f32x4*)(dp + 16 + k4 * 4);
            u2.q[k4] += *(const f32x4*)(dp + 32 + k4 * 4);
            u3.q[k4] += *(const f32x4*)(dp + 48 + k4 * 4);
        }
    }
    __syncthreads();
    if (w == 1) {
        float* dp = xred[0] + lane * 68;
        #pragma unroll
        for (int k4 = 0; k4 < 4; k4++) {
            *(f32x4*)(dp + k4 * 4)      = u0.q[k4];
            *(f32x4*)(dp + 16 + k4 * 4) = u1.q[k4];
            *(f32x4*)(dp + 32 + k4 * 4) = u2.q[k4];
            *(f32x4*)(dp + 48 + k4 * 4) = u3.q[k4];
        }
    }
    __syncthreads();
    if (w == 0) {
        const float* dp = xred[0] + lane * 68;
        #pragma unroll
        for (int k4 = 0; k4 < 4; k4++) {
            u0.q[k4] += *(const f32x4*)(dp + k4 * 4);
            u1.q[k4] += *(const f32x4*)(dp + 16 + k4 * 4);
            u2.q[k4] += *(const f32x4*)(dp + 32 + k4 * 4);
            u3.q[k4] += *(const f32x4*)(dp + 48 + k4 * 4);
        }
        float bv0 = bias[h * 128 + l31];
        float bv1 = bias[h * 128 + 32 + l31];
        float bv2 = bias[h * 128 + 64 + l31];
        float bv3 = bias[h * 128 + 96 + l31];
        #pragma unroll
        for (int r = 0; r < 16; r++) {
            int row = i0 + (r & 3) + 8 * (r >> 2) + 4 * half;
            float* op = out + (size_t)row * 1024 + h * 128 + l31;
            op[0]  = u0.v[r] + bv0;
            op[32] = u1.v[r] + bv1;
            op[64] = u2.v[r] + bv2;
            op[96] = u3.v[r] + bv3;
        }
    }
}

extern "C" void kernel_launch(void* const* d_in, const int* in_sizes, int n_in,
                              void* d_out, int out_size, void* d_ws, size_t ws_size,
                              hipStream_t stream) {
    (void)in_sizes; (void)n_in; (void)out_size; (void)ws_size;
    const float* x     = (const float*)d_in[0];
    const int*   graph = (const int*)d_in[1];
    const float* W     = (const float*)d_in[2];
    const float* wi    = (const float*)d_in[3];
    const float* wj    = (const float*)d_in[4];
    const float* Wr    = (const float*)d_in[5];
    const float* bias  = (const float*)d_in[6];
    float* out = (float*)d_out;

    char* ws = (char*)d_ws;
    unsigned int* maskJ = (unsigned int*)ws;              // 2 MB  [128 jw][4096 i]
    f16* hbT2  = (f16*)(ws + (2u << 20));                 // 8 MB  [8][(j>>4)*128+f][j&15]
    f16* Wht2  = (f16*)(ws + (10u << 20));                // 1 MB  swizzled
    f16* Wrt2  = (f16*)(ws + (11u << 20));                // 1 MB  swizzled
    f16* xh2   = (f16*)(ws + (12u << 20));                // 4 MB  [32][4096][16] swizzled
    float* a2    = (float*)(ws + (16u << 20));            // 128 KB
    float* b2    = a2 + 8 * 4096;
    float* ABpre = b2 + 8 * 4096;
    float* Bpre  = ABpre + 2 * 8 * 4096;
    unsigned int* M2e = (unsigned int*)(Bpre + 2 * 8 * 4096);

    hipLaunchKernelGGL(k_mask, dim3(1024), dim3(256), 0, stream, graph, maskJ, M2e);
    hipLaunchKernelGGL(k_pre, dim3(1536), dim3(256), 0, stream, x, xh2, W, Wht2, Wr, Wrt2);
    hipLaunchKernelGGL(k_gemm_h, dim3(512), dim3(256), 0, stream, xh2, Wht2, hbT2);
    hipLaunchKernelGGL(k_ab, dim3(128), dim3(256), 0, stream, hbT2, wi, wj, a2, b2, M2e);
    hipLaunchKernelGGL(k_prep, dim3(128), dim3(256), 0, stream, a2, b2, M2e, ABpre, Bpre);
    hipLaunchKernelGGL(k_main, dim3(1024), dim3(256), 0, stream, xh2, hbT2, Wrt2, maskJ,
                       ABpre, Bpre, bias, out);
}

// Round 6
// 3853.843 us; speedup vs baseline: 1.9155x; 1.9155x over previous
//
#include <hip/hip_runtime.h>
#include <hip/hip_fp16.h>

typedef _Float16 f16;
typedef _Float16 f16x8 __attribute__((ext_vector_type(8)));
typedef __fp16 h16x2 __attribute__((ext_vector_type(2)));
typedef float f32x4 __attribute__((ext_vector_type(4)));
typedef float f32x16 __attribute__((ext_vector_type(16)));

#define LOG2E 1.4426950408889634f
#define NSL 0.2f

// ---------------- Kernel 1: graph -> j-major transposed bitmask (+ init M2e) ----------------
// maskJ[jw][i] bit b = (graph[jw*32+b][i] > 0)
__global__ __launch_bounds__(256) void k_mask(const int* __restrict__ graph,
                                              unsigned int* __restrict__ maskJ,
                                              unsigned int* __restrict__ M2e) {
    if (blockIdx.x == 0 && threadIdx.x < 8) M2e[threadIdx.x] = 0x007FFFFFu;  // enc(-inf)
    __shared__ unsigned long long bal[4][64];
    int w = threadIdx.x >> 6;
    int lane = threadIdx.x & 63;
    int gw = blockIdx.x * 4 + w;
    int ti = gw & 63, tj = gw >> 6;
    int i0 = ti * 64, j0 = tj * 64;
    #pragma unroll 8
    for (int k = 0; k < 64; k++) {
        int g = graph[(j0 + k) * 4096 + i0 + lane];
        unsigned long long b = __ballot(g > 0);
        if (lane == 0) bal[w][k] = b;
    }
    __syncthreads();
    unsigned long long word = 0;
    #pragma unroll 8
    for (int k = 0; k < 64; k++) {
        word |= ((bal[w][k] >> lane) & 1ull) << k;
    }
    int jw = j0 >> 5;
    maskJ[(size_t)jw * 4096 + i0 + lane]       = (unsigned int)word;
    maskJ[(size_t)(jw + 1) * 4096 + i0 + lane] = (unsigned int)(word >> 32);
}

// ---------------- Kernel 2 (fused prep): xcvt + swizzled weight transposes ----------------
// out[((m>>4)*S + f)*16 + (m&15)] = in[m][f]   (direct MFMA-fragment layout)
__device__ void dev_transpose_sw(const float* __restrict__ in, f16* __restrict__ out,
                                 int C, int S, int bxx, int byy, int tid) {
    __shared__ float tile[32][33];
    int tx = tid & 31, ty = tid >> 5;
    int c0 = bxx * 32, r0 = byy * 32;
    for (int rr = ty; rr < 32; rr += 8)
        tile[rr][tx] = in[(r0 + rr) * C + c0 + tx];
    __syncthreads();
    for (int rr = ty; rr < 32; rr += 8) {
        int m = r0 + tx, f = c0 + rr;
        out[(size_t)((m >> 4) * S + f) * 16 + (m & 15)] = (f16)tile[tx][rr];
    }
}

__global__ __launch_bounds__(256) void k_pre(const float* __restrict__ x,
                                             f16* __restrict__ xh2,
                                             const float* __restrict__ W,
                                             f16* __restrict__ Wht2,
                                             const float* __restrict__ Wr,
                                             f16* __restrict__ Wrt2) {
    int bx = blockIdx.x;
    int tid = threadIdx.x;
    if (bx < 512) {
        int id = bx * 256 + tid;   // 131072
        int row = id & 4095, kt = id >> 12;
        const float4* xs = (const float4*)(x + (size_t)row * 512 + kt * 16);
        float4 u0 = xs[0], u1 = xs[1], u2 = xs[2], u3 = xs[3];
        union { int4 a[2]; h16x2 p[8]; } px;
        px.p[0] = __builtin_amdgcn_cvt_pkrtz(u0.x, u0.y);
        px.p[1] = __builtin_amdgcn_cvt_pkrtz(u0.z, u0.w);
        px.p[2] = __builtin_amdgcn_cvt_pkrtz(u1.x, u1.y);
        px.p[3] = __builtin_amdgcn_cvt_pkrtz(u1.z, u1.w);
        px.p[4] = __builtin_amdgcn_cvt_pkrtz(u2.x, u2.y);
        px.p[5] = __builtin_amdgcn_cvt_pkrtz(u2.z, u2.w);
        px.p[6] = __builtin_amdgcn_cvt_pkrtz(u3.x, u3.y);
        px.p[7] = __builtin_amdgcn_cvt_pkrtz(u3.z, u3.w);
        int4* d = (int4*)(xh2 + ((size_t)kt * 4096 + row) * 16);
        d[0] = px.a[0]; d[1] = px.a[1];
    } else if (bx < 1024) {
        int id = bx - 512;                       // W -> Wht2
        dev_transpose_sw(W, Wht2, 128, 128, id & 3, id >> 2, tid);
    } else {
        int id = bx - 1024;                      // Wr -> Wrt2
        dev_transpose_sw(Wr, Wrt2, 1024, 1024, id & 31, id >> 5, tid);
    }
}

// ---------------- Kernel 3: hbT2 swizzled [h][(j>>4)*128+f][j&15] ----------------
__global__ __launch_bounds__(256) void k_gemm_h(const f16* __restrict__ xh2,
                                                const f16* __restrict__ Wht2,
                                                f16* __restrict__ hbT2) {
    int bx = blockIdx.x;
    int h = bx & 7, jb = bx >> 3;
    int j0 = jb * 64;
    int tid = threadIdx.x;
    int w = tid >> 6, lane = tid & 63;
    int ln = lane & 15, q = lane >> 4;
    f32x4 acc[2][4] = {};
    for (int k0 = 0; k0 < 512; k0 += 32) {
        int kt = (k0 >> 4) + (q >> 1);
        int ko = (q & 1) * 8;
        f16x8 a0 = *(const f16x8*)(Wht2 + ((size_t)(h * 512 + k0) * 8
                                           + (size_t)(q >> 1) * 128 + w * 32 + ln) * 16 + ko);
        f16x8 a1 = *(const f16x8*)(Wht2 + ((size_t)(h * 512 + k0) * 8
                                           + (size_t)(q >> 1) * 128 + w * 32 + 16 + ln) * 16 + ko);
        f16x8 bfr[4];
        #pragma unroll
        for (int nt = 0; nt < 4; nt++) {
            bfr[nt] = *(const f16x8*)(xh2 + ((size_t)kt * 4096 + j0 + nt * 16 + ln) * 16 + ko);
        }
        #pragma unroll
        for (int nt = 0; nt < 4; nt++) {
            acc[0][nt] = __builtin_amdgcn_mfma_f32_16x16x32_f16(a0, bfr[nt], acc[0][nt], 0, 0, 0);
            acc[1][nt] = __builtin_amdgcn_mfma_f32_16x16x32_f16(a1, bfr[nt], acc[1][nt], 0, 0, 0);
        }
    }
    #pragma unroll
    for (int mt = 0; mt < 2; mt++)
        #pragma unroll
        for (int nt = 0; nt < 4; nt++) {
            #pragma unroll
            for (int r = 0; r < 4; r++) {
                int f = w * 32 + mt * 16 + q * 4 + r;
                hbT2[(size_t)h * 524288 + (size_t)((j0 >> 4) + nt) * 2048 + f * 16 + ln] =
                    (f16)acc[mt][nt][r];
            }
        }
}

// ---------------- Kernel 4: a2/b2 + per-head atomic max of b2 (encoded) ----------------
__global__ __launch_bounds__(256) void k_ab(const f16* __restrict__ hbT2,
                                            const float* __restrict__ wi,
                                            const float* __restrict__ wj,
                                            float* __restrict__ a2, float* __restrict__ b2,
                                            unsigned int* __restrict__ M2e) {
    __shared__ float swi[128], swj[128], red[256];
    int b = blockIdx.x;
    int h = b & 7, jc = b >> 3;
    int tid = threadIdx.x;
    if (tid < 128) { swi[tid] = wi[h * 128 + tid]; swj[tid] = wj[h * 128 + tid]; }
    __syncthreads();
    int j = jc * 256 + tid;
    float pa = 0.f, pb = 0.f;
    #pragma unroll 8
    for (int f = 0; f < 128; f++) {
        float v = (float)hbT2[(size_t)h * 524288 + (size_t)((j >> 4) * 128 + f) * 16 + (j & 15)];
        pa += v * swi[f];
        pb += v * swj[f];
    }
    a2[h * 4096 + j] = pa * LOG2E;
    float bb = pb * LOG2E;
    b2[h * 4096 + j] = bb;
    red[tid] = bb;
    __syncthreads();
    for (int s = 128; s > 0; s >>= 1) {
        if (tid < s) red[tid] = fmaxf(red[tid], red[tid + s]);
        __syncthreads();
    }
    if (tid == 0) {
        unsigned u = __float_as_uint(red[0]);
        unsigned enc = (u & 0x80000000u) ? ~u : (u | 0x80000000u);
        atomicMax(&M2e[h], enc);
    }
}

// ---------------- Kernel 5: exp tables ----------------
__global__ __launch_bounds__(256) void k_prep(const float* __restrict__ a2,
                                              const float* __restrict__ b2,
                                              const unsigned int* __restrict__ M2e,
                                              float* __restrict__ ABpre,
                                              float* __restrict__ Bpre) {
    int id = blockIdx.x * 256 + threadIdx.x;   // 32768
    int h = id >> 12;
    unsigned enc = M2e[h];
    unsigned u = (enc & 0x80000000u) ? (enc & 0x7FFFFFFFu) : ~enc;
    float M2 = __uint_as_float(u);
    float av = a2[id];
    float t = av + M2;
    float m2 = fmaxf(t, NSL * t);
    ((float2*)ABpre)[id] = make_float2(exp2f(av - m2), exp2f(NSL * av - m2));
    float bv = b2[id];
    ((float2*)Bpre)[id] = make_float2(exp2f(bv), exp2f(NSL * bv));
}

// ---------------- Kernel 6: main — zero-LDS-staging, low-reg (j-half x f-half per wave) ----------------
// Block = (h=bx&7 XCD-pinned, 32-i strip). Wave w: jh=w&1 (2048 j), fh=w>>1 (64 f).
// Per wave: 2 accs (32 regs) + 2x2 frag dbuf (16) -> spill-free under 128-reg cap.
// B-frags load directly from L2-resident swizzled hbT2 (contiguous 1 KB/instr). No j-loop barriers.
__global__ __launch_bounds__(256, 4) void k_main(const f16* __restrict__ xh2,
                                                 const f16* __restrict__ hbT2,
                                                 const f16* __restrict__ Wrt2,
                                                 const unsigned int* __restrict__ maskJ,
                                                 const float* __restrict__ ABpre,
                                                 const float* __restrict__ Bpre,
                                                 const float* __restrict__ bias,
                                                 float* __restrict__ out) {
    __shared__ float dred[64];
    __shared__ float xch[2][64 * 36];   // per-fh exchange, 16B-aligned rows

    int bx = blockIdx.x;
    int h = bx & 7, it = bx >> 3;
    int i0 = it * 32;
    int tid = threadIdx.x;
    int w = tid >> 6, lane = tid & 63;
    int l31 = lane & 31, half = lane >> 5;
    int jh = w & 1, fh = w >> 1;
    int i = i0 + l31;

    float2 Av = *(const float2*)(ABpre + 2 * (h * 4096 + i));
    float Ai = Av.x, Ai2 = Av.y;

    f32x16 acc0 = {}, acc1 = {};
    float dsum = 0.f;

    int J0 = jh * 2048;
    const f16* bb = hbT2 + (size_t)h * 524288
                    + ((size_t)(J0 >> 4) * 128 + fh * 64 + l31) * 16 + half * 8;
    const float* bp0 = Bpre + 2 * (h * 4096 + J0) + half * 16;
    const unsigned int* mrow = maskJ + (size_t)(J0 >> 5) * 4096 + i;

    f16x8 bfr[2][2];
    bfr[0][0] = *(const f16x8*)(bb);
    bfr[0][1] = *(const f16x8*)(bb + 512);

    for (int t = 0; t < 128; t++) {
        int cur = t & 1;
        if (t < 127) {   // register prefetch, distance 1
            const f16* s = bb + (size_t)(t + 1) * 2048;
            bfr[cur ^ 1][0] = *(const f16x8*)(s);
            bfr[cur ^ 1][1] = *(const f16x8*)(s + 512);
        }
        unsigned mw = mrow[(size_t)(t >> 1) * 4096] >> (((t & 1) << 4) + (half << 3));
        const float4* bp = (const float4*)(bp0 + t * 32);
        float4 q0 = bp[0], q1 = bp[1], q2 = bp[2], q3 = bp[3];

        union { f16x8 v; h16x2 p[4]; } af;
        float e0, e1;
        e0 = fmaxf(Ai * q0.x, Ai2 * q0.y); e1 = fmaxf(Ai * q0.z, Ai2 * q0.w);
        e0 = (mw & 1u) ? e0 : 0.f;  e1 = (mw & 2u) ? e1 : 0.f;
        dsum += e0 + e1; af.p[0] = __builtin_amdgcn_cvt_pkrtz(e0, e1);
        e0 = fmaxf(Ai * q1.x, Ai2 * q1.y); e1 = fmaxf(Ai * q1.z, Ai2 * q1.w);
        e0 = (mw & 4u) ? e0 : 0.f;  e1 = (mw & 8u) ? e1 : 0.f;
        dsum += e0 + e1; af.p[1] = __builtin_amdgcn_cvt_pkrtz(e0, e1);
        e0 = fmaxf(Ai * q2.x, Ai2 * q2.y); e1 = fmaxf(Ai * q2.z, Ai2 * q2.w);
        e0 = (mw & 16u) ? e0 : 0.f; e1 = (mw & 32u) ? e1 : 0.f;
        dsum += e0 + e1; af.p[2] = __builtin_amdgcn_cvt_pkrtz(e0, e1);
        e0 = fmaxf(Ai * q3.x, Ai2 * q3.y); e1 = fmaxf(Ai * q3.z, Ai2 * q3.w);
        e0 = (mw & 64u) ? e0 : 0.f; e1 = (mw & 128u) ? e1 : 0.f;
        dsum += e0 + e1; af.p[3] = __builtin_amdgcn_cvt_pkrtz(e0, e1);

        acc0 = __builtin_amdgcn_mfma_f32_32x32x16_f16(af.v, bfr[cur][0], acc0, 0, 0, 0);
        acc1 = __builtin_amdgcn_mfma_f32_32x32x16_f16(af.v, bfr[cur][1], acc1, 0, 0, 0);
    }

    // ---- denominator: only fh==0 waves publish (fh==1 computed identical P) ----
    dsum += __shfl(dsum, lane ^ 32);
    if (w < 2 && lane < 32) dred[jh * 32 + l31] = dsum;
    __syncthreads();
    {
        #pragma unroll
        for (int r = 0; r < 16; r++) {
            int row = (r & 3) + 8 * (r >> 2) + 4 * half;
            float inv = 1.0f / (dred[row] + dred[32 + row]);
            acc0[r] *= inv; acc1[r] *= inv;
        }
    }

    // ---- residual: acc += x @ Wr[:, h-slice]; k-half jh, f-half fh, direct fragment loads ----
    {
        #pragma unroll
        for (int kt = 0; kt < 16; kt++) {
            int ktt = jh * 16 + kt;
            f16x8 ax = *(const f16x8*)(xh2 + ((size_t)ktt * 4096 + i) * 16 + half * 8);
            const f16* wb = Wrt2 + ((size_t)ktt * 1024 + h * 128 + fh * 64 + l31) * 16 + half * 8;
            acc0 = __builtin_amdgcn_mfma_f32_32x32x16_f16(ax, *(const f16x8*)(wb), acc0, 0, 0, 0);
            acc1 = __builtin_amdgcn_mfma_f32_32x32x16_f16(ax, *(const f16x8*)(wb + 512), acc1, 0, 0, 0);
        }
    }

    // ---- cross-jh reduction: jh==1 waves write, jh==0 waves add + store ----
    union uu { f32x16 v; f32x4 q[4]; };
    uu u0, u1;
    u0.v = acc0; u1.v = acc1;
    __syncthreads();   // dred reads done
    if (jh == 1) {
        float* dp = xch[fh] + lane * 36;
        #pragma unroll
        for (int k4 = 0; k4 < 4; k4++) {
            *(f32x4*)(dp + k4 * 4)      = u0.q[k4];
            *(f32x4*)(dp + 16 + k4 * 4) = u1.q[k4];
        }
    }
    __syncthreads();
    if (jh == 0) {
        const float* dp = xch[fh] + lane * 36;
        #pragma unroll
        for (int k4 = 0; k4 < 4; k4++) {
            u0.q[k4] += *(const f32x4*)(dp + k4 * 4);
            u1.q[k4] += *(const f32x4*)(dp + 16 + k4 * 4);
        }
        int c0 = h * 128 + fh * 64 + l31;
        float bv0 = bias[c0];
        float bv1 = bias[c0 + 32];
        #pragma unroll
        for (int r = 0; r < 16; r++) {
            int row = i0 + (r & 3) + 8 * (r >> 2) + 4 * half;
            float* op = out + (size_t)row * 1024 + c0;
            op[0]  = u0.v[r] + bv0;
            op[32] = u1.v[r] + bv1;
        }
    }
}

extern "C" void kernel_launch(void* const* d_in, const int* in_sizes, int n_in,
                              void* d_out, int out_size, void* d_ws, size_t ws_size,
                              hipStream_t stream) {
    (void)in_sizes; (void)n_in; (void)out_size; (void)ws_size;
    const float* x     = (const float*)d_in[0];
    const int*   graph = (const int*)d_in[1];
    const float* W     = (const float*)d_in[2];
    const float* wi    = (const float*)d_in[3];
    const float* wj    = (const float*)d_in[4];
    const float* Wr    = (const float*)d_in[5];
    const float* bias  = (const float*)d_in[6];
    float* out = (float*)d_out;

    char* ws = (char*)d_ws;
    unsigned int* maskJ = (unsigned int*)ws;              // 2 MB  [128 jw][4096 i]
    f16* hbT2  = (f16*)(ws + (2u << 20));                 // 8 MB  [8][(j>>4)*128+f][j&15]
    f16* Wht2  = (f16*)(ws + (10u << 20));                // 1 MB  swizzled
    f16* Wrt2  = (f16*)(ws + (11u << 20));                // 1 MB  swizzled
    f16* xh2   = (f16*)(ws + (12u << 20));                // 4 MB  [32][4096][16] swizzled
    float* a2    = (float*)(ws + (16u << 20));            // 128 KB
    float* b2    = a2 + 8 * 4096;
    float* ABpre = b2 + 8 * 4096;
    float* Bpre  = ABpre + 2 * 8 * 4096;
    unsigned int* M2e = (unsigned int*)(Bpre + 2 * 8 * 4096);

    hipLaunchKernelGGL(k_mask, dim3(1024), dim3(256), 0, stream, graph, maskJ, M2e);
    hipLaunchKernelGGL(k_pre, dim3(1536), dim3(256), 0, stream, x, xh2, W, Wht2, Wr, Wrt2);
    hipLaunchKernelGGL(k_gemm_h, dim3(512), dim3(256), 0, stream, xh2, Wht2, hbT2);
    hipLaunchKernelGGL(k_ab, dim3(128), dim3(256), 0, stream, hbT2, wi, wj, a2, b2, M2e);
    hipLaunchKernelGGL(k_prep, dim3(128), dim3(256), 0, stream, a2, b2, M2e, ABpre, Bpre);
    hipLaunchKernelGGL(k_main, dim3(1024), dim3(256), 0, stream, xh2, hbT2, Wrt2, maskJ,
                       ABpre, Bpre, bias, out);
}

// Round 7
// 279.179 us; speedup vs baseline: 26.4416x; 13.8042x over previous
//
#include <hip/hip_runtime.h>
#include <hip/hip_fp16.h>

typedef _Float16 f16;
typedef _Float16 f16x8 __attribute__((ext_vector_type(8)));
typedef __fp16 h16x2 __attribute__((ext_vector_type(2)));
typedef float f32x4 __attribute__((ext_vector_type(4)));
typedef float f32x16 __attribute__((ext_vector_type(16)));

#define LOG2E 1.4426950408889634f
#define NSL 0.2f

// ---------------- Kernel 1: graph -> j-major transposed bitmask (+ init M2e) ----------------
// maskJ[jw][i] bit b = (graph[jw*32+b][i] > 0)
__global__ __launch_bounds__(256) void k_mask(const int* __restrict__ graph,
                                              unsigned int* __restrict__ maskJ,
                                              unsigned int* __restrict__ M2e) {
    if (blockIdx.x == 0 && threadIdx.x < 8) M2e[threadIdx.x] = 0x007FFFFFu;  // enc(-inf)
    __shared__ unsigned long long bal[4][64];
    int w = threadIdx.x >> 6;
    int lane = threadIdx.x & 63;
    int gw = blockIdx.x * 4 + w;
    int ti = gw & 63, tj = gw >> 6;
    int i0 = ti * 64, j0 = tj * 64;
    #pragma unroll 8
    for (int k = 0; k < 64; k++) {
        int g = graph[(j0 + k) * 4096 + i0 + lane];
        unsigned long long b = __ballot(g > 0);
        if (lane == 0) bal[w][k] = b;
    }
    __syncthreads();
    unsigned long long word = 0;
    #pragma unroll 8
    for (int k = 0; k < 64; k++) {
        word |= ((bal[w][k] >> lane) & 1ull) << k;
    }
    int jw = j0 >> 5;
    maskJ[(size_t)jw * 4096 + i0 + lane]       = (unsigned int)word;
    maskJ[(size_t)(jw + 1) * 4096 + i0 + lane] = (unsigned int)(word >> 32);
}

// ---------------- Kernel 2 (fused prep): xcvt + swizzled weight transposes ----------------
// out[((m>>4)*S + f)*16 + (m&15)] = in[m][f]   (direct MFMA-fragment layout)
__device__ void dev_transpose_sw(const float* __restrict__ in, f16* __restrict__ out,
                                 int C, int S, int bxx, int byy, int tid) {
    __shared__ float tile[32][33];
    int tx = tid & 31, ty = tid >> 5;
    int c0 = bxx * 32, r0 = byy * 32;
    for (int rr = ty; rr < 32; rr += 8)
        tile[rr][tx] = in[(r0 + rr) * C + c0 + tx];
    __syncthreads();
    for (int rr = ty; rr < 32; rr += 8) {
        int m = r0 + tx, f = c0 + rr;
        out[(size_t)((m >> 4) * S + f) * 16 + (m & 15)] = (f16)tile[tx][rr];
    }
}

__global__ __launch_bounds__(256) void k_pre(const float* __restrict__ x,
                                             f16* __restrict__ xh2,
                                             const float* __restrict__ W,
                                             f16* __restrict__ Wht2,
                                             const float* __restrict__ Wr,
                                             f16* __restrict__ Wrt2) {
    int bx = blockIdx.x;
    int tid = threadIdx.x;
    if (bx < 512) {
        int id = bx * 256 + tid;   // 131072
        int row = id & 4095, kt = id >> 12;
        const float4* xs = (const float4*)(x + (size_t)row * 512 + kt * 16);
        float4 u0 = xs[0], u1 = xs[1], u2 = xs[2], u3 = xs[3];
        union { int4 a[2]; h16x2 p[8]; } px;
        px.p[0] = __builtin_amdgcn_cvt_pkrtz(u0.x, u0.y);
        px.p[1] = __builtin_amdgcn_cvt_pkrtz(u0.z, u0.w);
        px.p[2] = __builtin_amdgcn_cvt_pkrtz(u1.x, u1.y);
        px.p[3] = __builtin_amdgcn_cvt_pkrtz(u1.z, u1.w);
        px.p[4] = __builtin_amdgcn_cvt_pkrtz(u2.x, u2.y);
        px.p[5] = __builtin_amdgcn_cvt_pkrtz(u2.z, u2.w);
        px.p[6] = __builtin_amdgcn_cvt_pkrtz(u3.x, u3.y);
        px.p[7] = __builtin_amdgcn_cvt_pkrtz(u3.z, u3.w);
        int4* d = (int4*)(xh2 + ((size_t)kt * 4096 + row) * 16);
        d[0] = px.a[0]; d[1] = px.a[1];
    } else if (bx < 1024) {
        int id = bx - 512;                       // W -> Wht2
        dev_transpose_sw(W, Wht2, 128, 128, id & 3, id >> 2, tid);
    } else {
        int id = bx - 1024;                      // Wr -> Wrt2
        dev_transpose_sw(Wr, Wrt2, 1024, 1024, id & 31, id >> 5, tid);
    }
}

// ---------------- Kernel 3: hbT2 swizzled [h][(j>>4)*128+f][j&15] ----------------
__global__ __launch_bounds__(256) void k_gemm_h(const f16* __restrict__ xh2,
                                                const f16* __restrict__ Wht2,
                                                f16* __restrict__ hbT2) {
    int bx = blockIdx.x;
    int h = bx & 7, jb = bx >> 3;
    int j0 = jb * 64;
    int tid = threadIdx.x;
    int w = tid >> 6, lane = tid & 63;
    int ln = lane & 15, q = lane >> 4;
    f32x4 acc[2][4] = {};
    for (int k0 = 0; k0 < 512; k0 += 32) {
        int kt = (k0 >> 4) + (q >> 1);
        int ko = (q & 1) * 8;
        f16x8 a0 = *(const f16x8*)(Wht2 + ((size_t)(h * 512 + k0) * 8
                                           + (size_t)(q >> 1) * 128 + w * 32 + ln) * 16 + ko);
        f16x8 a1 = *(const f16x8*)(Wht2 + ((size_t)(h * 512 + k0) * 8
                                           + (size_t)(q >> 1) * 128 + w * 32 + 16 + ln) * 16 + ko);
        f16x8 bfr[4];
        #pragma unroll
        for (int nt = 0; nt < 4; nt++) {
            bfr[nt] = *(const f16x8*)(xh2 + ((size_t)kt * 4096 + j0 + nt * 16 + ln) * 16 + ko);
        }
        #pragma unroll
        for (int nt = 0; nt < 4; nt++) {
            acc[0][nt] = __builtin_amdgcn_mfma_f32_16x16x32_f16(a0, bfr[nt], acc[0][nt], 0, 0, 0);
            acc[1][nt] = __builtin_amdgcn_mfma_f32_16x16x32_f16(a1, bfr[nt], acc[1][nt], 0, 0, 0);
        }
    }
    #pragma unroll
    for (int mt = 0; mt < 2; mt++)
        #pragma unroll
        for (int nt = 0; nt < 4; nt++) {
            #pragma unroll
            for (int r = 0; r < 4; r++) {
                int f = w * 32 + mt * 16 + q * 4 + r;
                hbT2[(size_t)h * 524288 + (size_t)((j0 >> 4) + nt) * 2048 + f * 16 + ln] =
                    (f16)acc[mt][nt][r];
            }
        }
}

// ---------------- Kernel 4: a2/b2 + per-head atomic max of b2 (encoded) ----------------
__global__ __launch_bounds__(256) void k_ab(const f16* __restrict__ hbT2,
                                            const float* __restrict__ wi,
                                            const float* __restrict__ wj,
                                            float* __restrict__ a2, float* __restrict__ b2,
                                            unsigned int* __restrict__ M2e) {
    __shared__ float swi[128], swj[128], red[256];
    int b = blockIdx.x;
    int h = b & 7, jc = b >> 3;
    int tid = threadIdx.x;
    if (tid < 128) { swi[tid] = wi[h * 128 + tid]; swj[tid] = wj[h * 128 + tid]; }
    __syncthreads();
    int j = jc * 256 + tid;
    float pa = 0.f, pb = 0.f;
    #pragma unroll 8
    for (int f = 0; f < 128; f++) {
        float v = (float)hbT2[(size_t)h * 524288 + (size_t)((j >> 4) * 128 + f) * 16 + (j & 15)];
        pa += v * swi[f];
        pb += v * swj[f];
    }
    a2[h * 4096 + j] = pa * LOG2E;
    float bb = pb * LOG2E;
    b2[h * 4096 + j] = bb;
    red[tid] = bb;
    __syncthreads();
    for (int s = 128; s > 0; s >>= 1) {
        if (tid < s) red[tid] = fmaxf(red[tid], red[tid + s]);
        __syncthreads();
    }
    if (tid == 0) {
        unsigned u = __float_as_uint(red[0]);
        unsigned enc = (u & 0x80000000u) ? ~u : (u | 0x80000000u);
        atomicMax(&M2e[h], enc);
    }
}

// ---------------- Kernel 5: exp tables ----------------
__global__ __launch_bounds__(256) void k_prep(const float* __restrict__ a2,
                                              const float* __restrict__ b2,
                                              const unsigned int* __restrict__ M2e,
                                              float* __restrict__ ABpre,
                                              float* __restrict__ Bpre) {
    int id = blockIdx.x * 256 + threadIdx.x;   // 32768
    int h = id >> 12;
    unsigned enc = M2e[h];
    unsigned u = (enc & 0x80000000u) ? (enc & 0x7FFFFFFFu) : ~enc;
    float M2 = __uint_as_float(u);
    float av = a2[id];
    float t = av + M2;
    float m2 = fmaxf(t, NSL * t);
    ((float2*)ABpre)[id] = make_float2(exp2f(av - m2), exp2f(NSL * av - m2));
    float bv = b2[id];
    ((float2*)Bpre)[id] = make_float2(exp2f(bv), exp2f(NSL * bv));
}

// ---------------- Kernel 6 helpers ----------------
#define PGEN(af, mw, shv, bpq)                                                   \
    {                                                                            \
        float4 q0 = (bpq)[0], q1 = (bpq)[1], q2 = (bpq)[2], q3 = (bpq)[3];       \
        unsigned m8 = (mw) >> (shv);                                             \
        float e0, e1;                                                            \
        e0 = fmaxf(Ai * q0.x, Ai2 * q0.y); e1 = fmaxf(Ai * q0.z, Ai2 * q0.w);    \
        e0 = (m8 & 1u) ? e0 : 0.f;  e1 = (m8 & 2u) ? e1 : 0.f;                   \
        dsum += e0 + e1; af.p[0] = __builtin_amdgcn_cvt_pkrtz(e0, e1);           \
        e0 = fmaxf(Ai * q1.x, Ai2 * q1.y); e1 = fmaxf(Ai * q1.z, Ai2 * q1.w);    \
        e0 = (m8 & 4u) ? e0 : 0.f;  e1 = (m8 & 8u) ? e1 : 0.f;                   \
        dsum += e0 + e1; af.p[1] = __builtin_amdgcn_cvt_pkrtz(e0, e1);           \
        e0 = fmaxf(Ai * q2.x, Ai2 * q2.y); e1 = fmaxf(Ai * q2.z, Ai2 * q2.w);    \
        e0 = (m8 & 16u) ? e0 : 0.f; e1 = (m8 & 32u) ? e1 : 0.f;                  \
        dsum += e0 + e1; af.p[2] = __builtin_amdgcn_cvt_pkrtz(e0, e1);           \
        e0 = fmaxf(Ai * q3.x, Ai2 * q3.y); e1 = fmaxf(Ai * q3.z, Ai2 * q3.w);    \
        e0 = (m8 & 64u) ? e0 : 0.f; e1 = (m8 & 128u) ? e1 : 0.f;                 \
        dsum += e0 + e1; af.p[3] = __builtin_amdgcn_cvt_pkrtz(e0, e1);           \
    }

// ---------------- Kernel 6: main — zero-LDS-staging, manually 2x-unrolled reg dbuf ----------------
// Block = (h=bx&7 XCD-pinned, 32-i strip). Wave w: jh=w&1 (2048 j), fh=w>>1 (64 f).
// All register buffers statically named (NO dynamic indexing -> no scratch).
__global__ __launch_bounds__(256, 4) void k_main(const f16* __restrict__ xh2,
                                                 const f16* __restrict__ hbT2,
                                                 const f16* __restrict__ Wrt2,
                                                 const unsigned int* __restrict__ maskJ,
                                                 const float* __restrict__ ABpre,
                                                 const float* __restrict__ Bpre,
                                                 const float* __restrict__ bias,
                                                 float* __restrict__ out) {
    __shared__ float dred[64];
    __shared__ float xch[2][64 * 36];   // per-fh exchange, 16B-aligned rows

    int bx = blockIdx.x;
    int h = bx & 7, it = bx >> 3;
    int i0 = it * 32;
    int tid = threadIdx.x;
    int w = tid >> 6, lane = tid & 63;
    int l31 = lane & 31, half = lane >> 5;
    int jh = w & 1, fh = w >> 1;
    int i = i0 + l31;

    float2 Av = *(const float2*)(ABpre + 2 * (h * 4096 + i));
    float Ai = Av.x, Ai2 = Av.y;

    f32x16 acc0 = {}, acc1 = {};
    float dsum = 0.f;

    int J0 = jh * 2048;
    const f16* bb = hbT2 + (size_t)h * 524288
                    + ((size_t)(J0 >> 4) * 128 + fh * 64 + l31) * 16 + half * 8;
    const float* bp0 = Bpre + 2 * (h * 4096 + J0) + half * 16;
    const unsigned int* mrow = maskJ + (size_t)(J0 >> 5) * 4096 + i;

    int sh0 = half << 3;            // even-t mask shift
    int sh1 = 16 + (half << 3);     // odd-t mask shift

    // statically-named double buffers
    f16x8 a0 = *(const f16x8*)(bb);
    f16x8 a1 = *(const f16x8*)(bb + 512);

    for (int tt = 0; tt < 64; tt++) {
        int t0 = tt * 2;
        unsigned mw = mrow[(size_t)tt * 4096];   // one u32 covers both bodies

        // prefetch t0+1 into b-buffers
        const f16* s1 = bb + (size_t)(t0 + 1) * 2048;
        f16x8 b0 = *(const f16x8*)(s1);
        f16x8 b1 = *(const f16x8*)(s1 + 512);

        // body even t0 (uses a0/a1)
        {
            union { f16x8 v; h16x2 p[4]; } af;
            const float4* bpq = (const float4*)(bp0 + t0 * 32);
            PGEN(af, mw, sh0, bpq);
            acc0 = __builtin_amdgcn_mfma_f32_32x32x16_f16(af.v, a0, acc0, 0, 0, 0);
            acc1 = __builtin_amdgcn_mfma_f32_32x32x16_f16(af.v, a1, acc1, 0, 0, 0);
        }

        // prefetch t0+2 into a-buffers (overruns ≤8 KB into workspace on last iter; never used)
        const f16* s2 = bb + (size_t)(t0 + 2) * 2048;
        a0 = *(const f16x8*)(s2);
        a1 = *(const f16x8*)(s2 + 512);

        // body odd t0+1 (uses b0/b1)
        {
            union { f16x8 v; h16x2 p[4]; } af;
            const float4* bpq = (const float4*)(bp0 + (t0 + 1) * 32);
            PGEN(af, mw, sh1, bpq);
            acc0 = __builtin_amdgcn_mfma_f32_32x32x16_f16(af.v, b0, acc0, 0, 0, 0);
            acc1 = __builtin_amdgcn_mfma_f32_32x32x16_f16(af.v, b1, acc1, 0, 0, 0);
        }
    }

    // ---- denominator: only fh==0 waves publish (fh==1 computed identical P) ----
    dsum += __shfl(dsum, lane ^ 32);
    if (w < 2 && lane < 32) dred[jh * 32 + l31] = dsum;
    __syncthreads();
    {
        #pragma unroll
        for (int r = 0; r < 16; r++) {
            int row = (r & 3) + 8 * (r >> 2) + 4 * half;
            float inv = 1.0f / (dred[row] + dred[32 + row]);
            acc0[r] *= inv; acc1[r] *= inv;
        }
    }

    // ---- residual: acc += x @ Wr[:, h-slice]; k-half jh, f-half fh, direct fragment loads ----
    {
        #pragma unroll
        for (int kt = 0; kt < 16; kt++) {
            int ktt = jh * 16 + kt;
            f16x8 ax = *(const f16x8*)(xh2 + ((size_t)ktt * 4096 + i) * 16 + half * 8);
            const f16* wb = Wrt2 + ((size_t)ktt * 1024 + h * 128 + fh * 64 + l31) * 16 + half * 8;
            acc0 = __builtin_amdgcn_mfma_f32_32x32x16_f16(ax, *(const f16x8*)(wb), acc0, 0, 0, 0);
            acc1 = __builtin_amdgcn_mfma_f32_32x32x16_f16(ax, *(const f16x8*)(wb + 512), acc1, 0, 0, 0);
        }
    }

    // ---- cross-jh reduction: jh==1 waves write, jh==0 waves add + store ----
    union uu { f32x16 v; f32x4 q[4]; };
    uu u0, u1;
    u0.v = acc0; u1.v = acc1;
    __syncthreads();   // dred reads done
    if (jh == 1) {
        float* dp = xch[fh] + lane * 36;
        #pragma unroll
        for (int k4 = 0; k4 < 4; k4++) {
            *(f32x4*)(dp + k4 * 4)      = u0.q[k4];
            *(f32x4*)(dp + 16 + k4 * 4) = u1.q[k4];
        }
    }
    __syncthreads();
    if (jh == 0) {
        const float* dp = xch[fh] + lane * 36;
        #pragma unroll
        for (int k4 = 0; k4 < 4; k4++) {
            u0.q[k4] += *(const f32x4*)(dp + k4 * 4);
            u1.q[k4] += *(const f32x4*)(dp + 16 + k4 * 4);
        }
        int c0 = h * 128 + fh * 64 + l31;
        float bv0 = bias[c0];
        float bv1 = bias[c0 + 32];
        #pragma unroll
        for (int r = 0; r < 16; r++) {
            int row = i0 + (r & 3) + 8 * (r >> 2) + 4 * half;
            float* op = out + (size_t)row * 1024 + c0;
            op[0]  = u0.v[r] + bv0;
            op[32] = u1.v[r] + bv1;
        }
    }
}

extern "C" void kernel_launch(void* const* d_in, const int* in_sizes, int n_in,
                              void* d_out, int out_size, void* d_ws, size_t ws_size,
                              hipStream_t stream) {
    (void)in_sizes; (void)n_in; (void)out_size; (void)ws_size;
    const float* x     = (const float*)d_in[0];
    const int*   graph = (const int*)d_in[1];
    const float* W     = (const float*)d_in[2];
    const float* wi    = (const float*)d_in[3];
    const float* wj    = (const float*)d_in[4];
    const float* Wr    = (const float*)d_in[5];
    const float* bias  = (const float*)d_in[6];
    float* out = (float*)d_out;

    char* ws = (char*)d_ws;
    unsigned int* maskJ = (unsigned int*)ws;              // 2 MB  [128 jw][4096 i]
    f16* hbT2  = (f16*)(ws + (2u << 20));                 // 8 MB  [8][(j>>4)*128+f][j&15]
    f16* Wht2  = (f16*)(ws + (10u << 20));                // 1 MB  swizzled
    f16* Wrt2  = (f16*)(ws + (11u << 20));                // 1 MB  swizzled
    f16* xh2   = (f16*)(ws + (12u << 20));                // 4 MB  [32][4096][16] swizzled
    float* a2    = (float*)(ws + (16u << 20));            // 128 KB
    float* b2    = a2 + 8 * 4096;
    float* ABpre = b2 + 8 * 4096;
    float* Bpre  = ABpre + 2 * 8 * 4096;
    unsigned int* M2e = (unsigned int*)(Bpre + 2 * 8 * 4096);

    hipLaunchKernelGGL(k_mask, dim3(1024), dim3(256), 0, stream, graph, maskJ, M2e);
    hipLaunchKernelGGL(k_pre, dim3(1536), dim3(256), 0, stream, x, xh2, W, Wht2, Wr, Wrt2);
    hipLaunchKernelGGL(k_gemm_h, dim3(512), dim3(256), 0, stream, xh2, Wht2, hbT2);
    hipLaunchKernelGGL(k_ab, dim3(128), dim3(256), 0, stream, hbT2, wi, wj, a2, b2, M2e);
    hipLaunchKernelGGL(k_prep, dim3(128), dim3(256), 0, stream, a2, b2, M2e, ABpre, Bpre);
    hipLaunchKernelGGL(k_main, dim3(1024), dim3(256), 0, stream, xh2, hbT2, Wrt2, maskJ,
                       ABpre, Bpre, bias, out);
}

// Round 8
// 266.443 us; speedup vs baseline: 27.7054x; 1.0478x over previous
//
#include <hip/hip_runtime.h>
#include <hip/hip_fp16.h>

typedef _Float16 f16;
typedef _Float16 f16x8 __attribute__((ext_vector_type(8)));
typedef __fp16 h16x2 __attribute__((ext_vector_type(2)));
typedef float f32x4 __attribute__((ext_vector_type(4)));
typedef float f32x16 __attribute__((ext_vector_type(16)));

#define LOG2E 1.4426950408889634f
#define NSL 0.2f

// ---------------- Kernel 1: graph -> j-major transposed bitmask (+ init M2e) ----------------
// maskJ[jw][i] bit b = (graph[jw*32+b][i] > 0)
__global__ __launch_bounds__(256) void k_mask(const int* __restrict__ graph,
                                              unsigned int* __restrict__ maskJ,
                                              unsigned int* __restrict__ M2e) {
    if (blockIdx.x == 0 && threadIdx.x < 8) M2e[threadIdx.x] = 0x007FFFFFu;  // enc(-inf)
    __shared__ unsigned long long bal[4][64];
    int w = threadIdx.x >> 6;
    int lane = threadIdx.x & 63;
    int gw = blockIdx.x * 4 + w;
    int ti = gw & 63, tj = gw >> 6;
    int i0 = ti * 64, j0 = tj * 64;
    #pragma unroll 8
    for (int k = 0; k < 64; k++) {
        int g = graph[(j0 + k) * 4096 + i0 + lane];
        unsigned long long b = __ballot(g > 0);
        if (lane == 0) bal[w][k] = b;
    }
    __syncthreads();
    unsigned long long word = 0;
    #pragma unroll 8
    for (int k = 0; k < 64; k++) {
        word |= ((bal[w][k] >> lane) & 1ull) << k;
    }
    int jw = j0 >> 5;
    maskJ[(size_t)jw * 4096 + i0 + lane]       = (unsigned int)word;
    maskJ[(size_t)(jw + 1) * 4096 + i0 + lane] = (unsigned int)(word >> 32);
}

// ---------------- Kernel 2 (fused prep): xcvt + swizzled weight transposes ----------------
// out[((m>>4)*S + f)*16 + (m&15)] = in[m][f]   (direct MFMA-fragment layout)
__device__ void dev_transpose_sw(const float* __restrict__ in, f16* __restrict__ out,
                                 int C, int S, int bxx, int byy, int tid) {
    __shared__ float tile[32][33];
    int tx = tid & 31, ty = tid >> 5;
    int c0 = bxx * 32, r0 = byy * 32;
    for (int rr = ty; rr < 32; rr += 8)
        tile[rr][tx] = in[(r0 + rr) * C + c0 + tx];
    __syncthreads();
    for (int rr = ty; rr < 32; rr += 8) {
        int m = r0 + tx, f = c0 + rr;
        out[(size_t)((m >> 4) * S + f) * 16 + (m & 15)] = (f16)tile[tx][rr];
    }
}

__global__ __launch_bounds__(256) void k_pre(const float* __restrict__ x,
                                             f16* __restrict__ xh2,
                                             const float* __restrict__ W,
                                             f16* __restrict__ Wht2,
                                             const float* __restrict__ Wr,
                                             f16* __restrict__ Wrt2) {
    int bx = blockIdx.x;
    int tid = threadIdx.x;
    if (bx < 512) {
        int id = bx * 256 + tid;   // 131072
        int row = id & 4095, kt = id >> 12;
        const float4* xs = (const float4*)(x + (size_t)row * 512 + kt * 16);
        float4 u0 = xs[0], u1 = xs[1], u2 = xs[2], u3 = xs[3];
        union { int4 a[2]; h16x2 p[8]; } px;
        px.p[0] = __builtin_amdgcn_cvt_pkrtz(u0.x, u0.y);
        px.p[1] = __builtin_amdgcn_cvt_pkrtz(u0.z, u0.w);
        px.p[2] = __builtin_amdgcn_cvt_pkrtz(u1.x, u1.y);
        px.p[3] = __builtin_amdgcn_cvt_pkrtz(u1.z, u1.w);
        px.p[4] = __builtin_amdgcn_cvt_pkrtz(u2.x, u2.y);
        px.p[5] = __builtin_amdgcn_cvt_pkrtz(u2.z, u2.w);
        px.p[6] = __builtin_amdgcn_cvt_pkrtz(u3.x, u3.y);
        px.p[7] = __builtin_amdgcn_cvt_pkrtz(u3.z, u3.w);
        int4* d = (int4*)(xh2 + ((size_t)kt * 4096 + row) * 16);
        d[0] = px.a[0]; d[1] = px.a[1];
    } else if (bx < 1024) {
        int id = bx - 512;                       // W -> Wht2
        dev_transpose_sw(W, Wht2, 128, 128, id & 3, id >> 2, tid);
    } else {
        int id = bx - 1024;                      // Wr -> Wrt2
        dev_transpose_sw(Wr, Wrt2, 1024, 1024, id & 31, id >> 5, tid);
    }
}

// ---------------- Kernel 3: hbT2 swizzled [h][(j>>4)*128+f][j&15] ----------------
__global__ __launch_bounds__(256) void k_gemm_h(const f16* __restrict__ xh2,
                                                const f16* __restrict__ Wht2,
                                                f16* __restrict__ hbT2) {
    int bx = blockIdx.x;
    int h = bx & 7, jb = bx >> 3;
    int j0 = jb * 64;
    int tid = threadIdx.x;
    int w = tid >> 6, lane = tid & 63;
    int ln = lane & 15, q = lane >> 4;
    f32x4 acc[2][4] = {};
    for (int k0 = 0; k0 < 512; k0 += 32) {
        int kt = (k0 >> 4) + (q >> 1);
        int ko = (q & 1) * 8;
        f16x8 a0 = *(const f16x8*)(Wht2 + ((size_t)(h * 512 + k0) * 8
                                           + (size_t)(q >> 1) * 128 + w * 32 + ln) * 16 + ko);
        f16x8 a1 = *(const f16x8*)(Wht2 + ((size_t)(h * 512 + k0) * 8
                                           + (size_t)(q >> 1) * 128 + w * 32 + 16 + ln) * 16 + ko);
        f16x8 bfr[4];
        #pragma unroll
        for (int nt = 0; nt < 4; nt++) {
            bfr[nt] = *(const f16x8*)(xh2 + ((size_t)kt * 4096 + j0 + nt * 16 + ln) * 16 + ko);
        }
        #pragma unroll
        for (int nt = 0; nt < 4; nt++) {
            acc[0][nt] = __builtin_amdgcn_mfma_f32_16x16x32_f16(a0, bfr[nt], acc[0][nt], 0, 0, 0);
            acc[1][nt] = __builtin_amdgcn_mfma_f32_16x16x32_f16(a1, bfr[nt], acc[1][nt], 0, 0, 0);
        }
    }
    #pragma unroll
    for (int mt = 0; mt < 2; mt++)
        #pragma unroll
        for (int nt = 0; nt < 4; nt++) {
            #pragma unroll
            for (int r = 0; r < 4; r++) {
                int f = w * 32 + mt * 16 + q * 4 + r;
                hbT2[(size_t)h * 524288 + (size_t)((j0 >> 4) + nt) * 2048 + f * 16 + ln] =
                    (f16)acc[mt][nt][r];
            }
        }
}

// ---------------- Kernel 4: a2/b2 + per-head atomic max of b2 (encoded) ----------------
__global__ __launch_bounds__(256) void k_ab(const f16* __restrict__ hbT2,
                                            const float* __restrict__ wi,
                                            const float* __restrict__ wj,
                                            float* __restrict__ a2, float* __restrict__ b2,
                                            unsigned int* __restrict__ M2e) {
    __shared__ float swi[128], swj[128], red[256];
    int b = blockIdx.x;
    int h = b & 7, jc = b >> 3;
    int tid = threadIdx.x;
    if (tid < 128) { swi[tid] = wi[h * 128 + tid]; swj[tid] = wj[h * 128 + tid]; }
    __syncthreads();
    int j = jc * 256 + tid;
    float pa = 0.f, pb = 0.f;
    #pragma unroll 8
    for (int f = 0; f < 128; f++) {
        float v = (float)hbT2[(size_t)h * 524288 + (size_t)((j >> 4) * 128 + f) * 16 + (j & 15)];
        pa += v * swi[f];
        pb += v * swj[f];
    }
    a2[h * 4096 + j] = pa * LOG2E;
    float bb = pb * LOG2E;
    b2[h * 4096 + j] = bb;
    red[tid] = bb;
    __syncthreads();
    for (int s = 128; s > 0; s >>= 1) {
        if (tid < s) red[tid] = fmaxf(red[tid], red[tid + s]);
        __syncthreads();
    }
    if (tid == 0) {
        unsigned u = __float_as_uint(red[0]);
        unsigned enc = (u & 0x80000000u) ? ~u : (u | 0x80000000u);
        atomicMax(&M2e[h], enc);
    }
}

// ---------------- Kernel 5: exp tables ----------------
__global__ __launch_bounds__(256) void k_prep(const float* __restrict__ a2,
                                              const float* __restrict__ b2,
                                              const unsigned int* __restrict__ M2e,
                                              float* __restrict__ ABpre,
                                              float* __restrict__ Bpre) {
    int id = blockIdx.x * 256 + threadIdx.x;   // 32768
    int h = id >> 12;
    unsigned enc = M2e[h];
    unsigned u = (enc & 0x80000000u) ? (enc & 0x7FFFFFFFu) : ~enc;
    float M2 = __uint_as_float(u);
    float av = a2[id];
    float t = av + M2;
    float m2 = fmaxf(t, NSL * t);
    ((float2*)ABpre)[id] = make_float2(exp2f(av - m2), exp2f(NSL * av - m2));
    float bv = b2[id];
    ((float2*)Bpre)[id] = make_float2(exp2f(bv), exp2f(NSL * bv));
}

// ---------------- Kernel 6 helpers ----------------
#define PGEN(af, mw, shv, bpq)                                                   \
    {                                                                            \
        float4 q0 = (bpq)[0], q1 = (bpq)[1], q2 = (bpq)[2], q3 = (bpq)[3];       \
        unsigned m8 = (mw) >> (shv);                                             \
        float e0, e1;                                                            \
        e0 = fmaxf(Ai * q0.x, Ai2 * q0.y); e1 = fmaxf(Ai * q0.z, Ai2 * q0.w);    \
        e0 = (m8 & 1u) ? e0 : 0.f;  e1 = (m8 & 2u) ? e1 : 0.f;                   \
        dsum += e0 + e1; af.p[0] = __builtin_amdgcn_cvt_pkrtz(e0, e1);           \
        e0 = fmaxf(Ai * q1.x, Ai2 * q1.y); e1 = fmaxf(Ai * q1.z, Ai2 * q1.w);    \
        e0 = (m8 & 4u) ? e0 : 0.f;  e1 = (m8 & 8u) ? e1 : 0.f;                   \
        dsum += e0 + e1; af.p[1] = __builtin_amdgcn_cvt_pkrtz(e0, e1);           \
        e0 = fmaxf(Ai * q2.x, Ai2 * q2.y); e1 = fmaxf(Ai * q2.z, Ai2 * q2.w);    \
        e0 = (m8 & 16u) ? e0 : 0.f; e1 = (m8 & 32u) ? e1 : 0.f;                  \
        dsum += e0 + e1; af.p[2] = __builtin_amdgcn_cvt_pkrtz(e0, e1);           \
        e0 = fmaxf(Ai * q3.x, Ai2 * q3.y); e1 = fmaxf(Ai * q3.z, Ai2 * q3.w);    \
        e0 = (m8 & 64u) ? e0 : 0.f; e1 = (m8 & 128u) ? e1 : 0.f;                 \
        dsum += e0 + e1; af.p[3] = __builtin_amdgcn_cvt_pkrtz(e0, e1);           \
    }

// ---------------- Kernel 6: main — full-f waves (1 PGEN feeds 4 MFMAs), static reg dbuf ----------------
// Block = (h=bx&7 XCD-pinned, 32-i strip). Wave w = j-quarter (1024 j), full 128 f.
// No P-gen duplication. All register buffers statically named. No j-loop barriers.
__global__ __launch_bounds__(256, 3) void k_main(const f16* __restrict__ xh2,
                                                 const f16* __restrict__ hbT2,
                                                 const f16* __restrict__ Wrt2,
                                                 const unsigned int* __restrict__ maskJ,
                                                 const float* __restrict__ ABpre,
                                                 const float* __restrict__ Bpre,
                                                 const float* __restrict__ bias,
                                                 float* __restrict__ out) {
    __shared__ float xred[2][64 * 68];   // 34816 B
    __shared__ float dred[128];

    int bx = blockIdx.x;
    int h = bx & 7, it = bx >> 3;
    int i0 = it * 32;
    int tid = threadIdx.x;
    int w = tid >> 6, lane = tid & 63;
    int l31 = lane & 31, half = lane >> 5;
    int i = i0 + l31;

    float2 Av = *(const float2*)(ABpre + 2 * (h * 4096 + i));
    float Ai = Av.x, Ai2 = Av.y;

    f32x16 acc0 = {}, acc1 = {}, acc2 = {}, acc3 = {};
    float dsum = 0.f;

    int J0 = w * 1024;
    const f16* bb = hbT2 + (size_t)h * 524288 + ((size_t)(J0 >> 4) * 128 + l31) * 16 + half * 8;
    const float* bp0 = Bpre + 2 * (h * 4096 + J0) + half * 16;
    const unsigned int* mrow = maskJ + (size_t)(J0 >> 5) * 4096 + i;

    int sh0 = half << 3;            // even-t mask shift
    int sh1 = 16 + (half << 3);     // odd-t mask shift

    // statically-named double buffers (4 frags = 128 f)
    f16x8 fa0 = *(const f16x8*)(bb);
    f16x8 fa1 = *(const f16x8*)(bb + 512);
    f16x8 fa2 = *(const f16x8*)(bb + 1024);
    f16x8 fa3 = *(const f16x8*)(bb + 1536);

    for (int tt = 0; tt < 32; tt++) {
        int t0 = tt * 2;
        unsigned mw = mrow[(size_t)tt * 4096];   // one u32 covers both bodies

        // prefetch t0+1 into b-buffers
        const f16* s1 = bb + (size_t)(t0 + 1) * 2048;
        f16x8 fb0 = *(const f16x8*)(s1);
        f16x8 fb1 = *(const f16x8*)(s1 + 512);
        f16x8 fb2 = *(const f16x8*)(s1 + 1024);
        f16x8 fb3 = *(const f16x8*)(s1 + 1536);

        // body even t0 (uses a-buffers)
        {
            union { f16x8 v; h16x2 p[4]; } af;
            const float4* bpq = (const float4*)(bp0 + t0 * 32);
            PGEN(af, mw, sh0, bpq);
            acc0 = __builtin_amdgcn_mfma_f32_32x32x16_f16(af.v, fa0, acc0, 0, 0, 0);
            acc1 = __builtin_amdgcn_mfma_f32_32x32x16_f16(af.v, fa1, acc1, 0, 0, 0);
            acc2 = __builtin_amdgcn_mfma_f32_32x32x16_f16(af.v, fa2, acc2, 0, 0, 0);
            acc3 = __builtin_amdgcn_mfma_f32_32x32x16_f16(af.v, fa3, acc3, 0, 0, 0);
        }

        // prefetch t0+2 into a-buffers (last-iter overrun stays inside workspace; never used)
        const f16* s2 = bb + (size_t)(t0 + 2) * 2048;
        fa0 = *(const f16x8*)(s2);
        fa1 = *(const f16x8*)(s2 + 512);
        fa2 = *(const f16x8*)(s2 + 1024);
        fa3 = *(const f16x8*)(s2 + 1536);

        // body odd t0+1 (uses b-buffers)
        {
            union { f16x8 v; h16x2 p[4]; } af;
            const float4* bpq = (const float4*)(bp0 + (t0 + 1) * 32);
            PGEN(af, mw, sh1, bpq);
            acc0 = __builtin_amdgcn_mfma_f32_32x32x16_f16(af.v, fb0, acc0, 0, 0, 0);
            acc1 = __builtin_amdgcn_mfma_f32_32x32x16_f16(af.v, fb1, acc1, 0, 0, 0);
            acc2 = __builtin_amdgcn_mfma_f32_32x32x16_f16(af.v, fb2, acc2, 0, 0, 0);
            acc3 = __builtin_amdgcn_mfma_f32_32x32x16_f16(af.v, fb3, acc3, 0, 0, 0);
        }
    }

    // ---- denominator: combine j-halves in-wave, then cross-wave via LDS ----
    dsum += __shfl(dsum, lane ^ 32);
    if (lane < 32) dred[w * 32 + l31] = dsum;
    __syncthreads();
    {
        #pragma unroll
        for (int r = 0; r < 16; r++) {
            int row = (r & 3) + 8 * (r >> 2) + 4 * half;
            float s = dred[row] + dred[32 + row] + dred[64 + row] + dred[96 + row];
            float inv = 1.0f / s;
            acc0[r] *= inv; acc1[r] *= inv; acc2[r] *= inv; acc3[r] *= inv;
        }
    }

    // ---- residual: acc += x @ Wr[:, h-slice]; k-quarter per wave, direct fragment loads ----
    {
        #pragma unroll
        for (int kt = 0; kt < 8; kt++) {
            int ktt = w * 8 + kt;
            f16x8 ax = *(const f16x8*)(xh2 + ((size_t)ktt * 4096 + i) * 16 + half * 8);
            const f16* wb = Wrt2 + ((size_t)ktt * 1024 + h * 128 + l31) * 16 + half * 8;
            acc0 = __builtin_amdgcn_mfma_f32_32x32x16_f16(ax, *(const f16x8*)(wb), acc0, 0, 0, 0);
            acc1 = __builtin_amdgcn_mfma_f32_32x32x16_f16(ax, *(const f16x8*)(wb + 512), acc1, 0, 0, 0);
            acc2 = __builtin_amdgcn_mfma_f32_32x32x16_f16(ax, *(const f16x8*)(wb + 1024), acc2, 0, 0, 0);
            acc3 = __builtin_amdgcn_mfma_f32_32x32x16_f16(ax, *(const f16x8*)(wb + 1536), acc3, 0, 0, 0);
        }
    }

    // ---- cross-wave O reduction: (w2,w3)->(w0,w1), then w1->w0; w0 stores ----
    union uu { f32x16 v; f32x4 q[4]; };
    uu u0, u1, u2, u3;
    u0.v = acc0; u1.v = acc1; u2.v = acc2; u3.v = acc3;
    __syncthreads();   // dred reads done
    if (w >= 2) {
        float* dp = xred[w - 2] + lane * 68;
        #pragma unroll
        for (int k4 = 0; k4 < 4; k4++) {
            *(f32x4*)(dp + k4 * 4)      = u0.q[k4];
            *(f32x4*)(dp + 16 + k4 * 4) = u1.q[k4];
            *(f32x4*)(dp + 32 + k4 * 4) = u2.q[k4];
            *(f32x4*)(dp + 48 + k4 * 4) = u3.q[k4];
        }
    }
    __syncthreads();
    if (w < 2) {
        const float* dp = xred[w] + lane * 68;
        #pragma unroll
        for (int k4 = 0; k4 < 4; k4++) {
            u0.q[k4] += *(const f32x4*)(dp + k4 * 4);
            u1.q[k4] += *(const f32x4*)(dp + 16 + k4 * 4);
            u2.q[k4] += *(const f32x4*)(dp + 32 + k4 * 4);
            u3.q[k4] += *(const f32x4*)(dp + 48 + k4 * 4);
        }
    }
    __syncthreads();
    if (w == 1) {
        float* dp = xred[0] + lane * 68;
        #pragma unroll
        for (int k4 = 0; k4 < 4; k4++) {
            *(f32x4*)(dp + k4 * 4)      = u0.q[k4];
            *(f32x4*)(dp + 16 + k4 * 4) = u1.q[k4];
            *(f32x4*)(dp + 32 + k4 * 4) = u2.q[k4];
            *(f32x4*)(dp + 48 + k4 * 4) = u3.q[k4];
        }
    }
    __syncthreads();
    if (w == 0) {
        const float* dp = xred[0] + lane * 68;
        #pragma unroll
        for (int k4 = 0; k4 < 4; k4++) {
            u0.q[k4] += *(const f32x4*)(dp + k4 * 4);
            u1.q[k4] += *(const f32x4*)(dp + 16 + k4 * 4);
            u2.q[k4] += *(const f32x4*)(dp + 32 + k4 * 4);
            u3.q[k4] += *(const f32x4*)(dp + 48 + k4 * 4);
        }
        float bv0 = bias[h * 128 + l31];
        float bv1 = bias[h * 128 + 32 + l31];
        float bv2 = bias[h * 128 + 64 + l31];
        float bv3 = bias[h * 128 + 96 + l31];
        #pragma unroll
        for (int r = 0; r < 16; r++) {
            int row = i0 + (r & 3) + 8 * (r >> 2) + 4 * half;
            float* op = out + (size_t)row * 1024 + h * 128 + l31;
            op[0]  = u0.v[r] + bv0;
            op[32] = u1.v[r] + bv1;
            op[64] = u2.v[r] + bv2;
            op[96] = u3.v[r] + bv3;
        }
    }
}

extern "C" void kernel_launch(void* const* d_in, const int* in_sizes, int n_in,
                              void* d_out, int out_size, void* d_ws, size_t ws_size,
                              hipStream_t stream) {
    (void)in_sizes; (void)n_in; (void)out_size; (void)ws_size;
    const float* x     = (const float*)d_in[0];
    const int*   graph = (const int*)d_in[1];
    const float* W     = (const float*)d_in[2];
    const float* wi    = (const float*)d_in[3];
    const float* wj    = (const float*)d_in[4];
    const float* Wr    = (const float*)d_in[5];
    const float* bias  = (const float*)d_in[6];
    float* out = (float*)d_out;

    char* ws = (char*)d_ws;
    unsigned int* maskJ = (unsigned int*)ws;              // 2 MB  [128 jw][4096 i]
    f16* hbT2  = (f16*)(ws + (2u << 20));                 // 8 MB  [8][(j>>4)*128+f][j&15]
    f16* Wht2  = (f16*)(ws + (10u << 20));                // 1 MB  swizzled
    f16* Wrt2  = (f16*)(ws + (11u << 20));                // 1 MB  swizzled
    f16* xh2   = (f16*)(ws + (12u << 20));                // 4 MB  [32][4096][16] swizzled
    float* a2    = (float*)(ws + (16u << 20));            // 128 KB
    float* b2    = a2 + 8 * 4096;
    float* ABpre = b2 + 8 * 4096;
    float* Bpre  = ABpre + 2 * 8 * 4096;
    unsigned int* M2e = (unsigned int*)(Bpre + 2 * 8 * 4096);

    hipLaunchKernelGGL(k_mask, dim3(1024), dim3(256), 0, stream, graph, maskJ, M2e);
    hipLaunchKernelGGL(k_pre, dim3(1536), dim3(256), 0, stream, x, xh2, W, Wht2, Wr, Wrt2);
    hipLaunchKernelGGL(k_gemm_h, dim3(512), dim3(256), 0, stream, xh2, Wht2, hbT2);
    hipLaunchKernelGGL(k_ab, dim3(128), dim3(256), 0, stream, hbT2, wi, wj, a2, b2, M2e);
    hipLaunchKernelGGL(k_prep, dim3(128), dim3(256), 0, stream, a2, b2, M2e, ABpre, Bpre);
    hipLaunchKernelGGL(k_main, dim3(1024), dim3(256), 0, stream, xh2, hbT2, Wrt2, maskJ,
                       ABpre, Bpre, bias, out);
}